// Round 7
// baseline (741.146 us; speedup 1.0000x reference)
//
#include <hip/hip_runtime.h>

// mLSTM  S=256 B=64 F=H=512 L=4
// v7: gemm LDS laid out in READ ORDER (linear lane*16 ds_read_b128, zero conflicts
//     by construction); stats fused into scan (sscan_k, half-wave-exact reductions);
//     fp32 hbuf dropped (bf16 in-place residual in Abf).
//   gemm_k  : Z = A @ W^T + bias (bf16 MFMA 32x32x16, 128x128 tile, BK=64)
//   sscan_k : phase1 LN stats gates 1-4 + sum_k (32 thr/row exact), phase2 chunk scan
//   scanB_k : exact fp32 cross-chunk combine -> n0/chunk
//   normh_k : inline stats q,o; n = n_loc + P*n0; ||n||; h = o*tanh(q*n_hat)+res(bf16)

typedef unsigned short u16;
typedef unsigned int   u32;
typedef short s8v  __attribute__((ext_vector_type(8)));   // 8 x bf16 (4 VGPRs)
typedef float f16v __attribute__((ext_vector_type(16)));  // 32x32 MFMA accum

#define S_    256
#define B_    64
#define F_    512
#define H_    512
#define L_    4
#define NG    3072          // 6*H
#define RALL  16384         // S*B
#define CH    16            // scan chunk length
#define INV_SQRT_H 0.044194173824159216f

__device__ __forceinline__ float bu2f(u16 u) {
    union { u32 i; float f; } z; z.i = ((u32)u) << 16; return z.f;
}
__device__ __forceinline__ u16 f2bf(float f) {
    union { float f; u32 i; } z; z.f = f;
    u32 r = (z.i + 0x7FFFu + ((z.i >> 16) & 1u)) >> 16;
    return (u16)r;
}
__device__ __forceinline__ float sigm(float x)  { return 1.0f / (1.0f + __expf(-x)); }
__device__ __forceinline__ float tanhf_(float x){ return 2.0f / (1.0f + __expf(-2.0f * x)) - 1.0f; }
__device__ __forceinline__ float wred64(float v) {
    #pragma unroll
    for (int m = 1; m < 64; m <<= 1) v += __shfl_xor(v, m);
    return v;
}
__device__ __forceinline__ float wred32(float v) {   // reduce within 32-lane halves
    #pragma unroll
    for (int m = 1; m < 32; m <<= 1) v += __shfl_xor(v, m);
    return v;
}
__device__ __forceinline__ void gl_lds16(const u16* g, u16* l) {
    __builtin_amdgcn_global_load_lds((const __attribute__((address_space(1))) u32*)g,
                                     (__attribute__((address_space(3))) u32*)l, 16, 0, 0);
}
__device__ __forceinline__ void unp8(uint4 u, float* f) {
    f[0] = bu2f((u16)(u.x & 0xffff)); f[1] = bu2f((u16)(u.x >> 16));
    f[2] = bu2f((u16)(u.y & 0xffff)); f[3] = bu2f((u16)(u.y >> 16));
    f[4] = bu2f((u16)(u.z & 0xffff)); f[5] = bu2f((u16)(u.z >> 16));
    f[6] = bu2f((u16)(u.w & 0xffff)); f[7] = bu2f((u16)(u.w >> 16));
}
__device__ __forceinline__ uint4 pck8(const float* f) {
    uint4 u;
    u.x = (u32)f2bf(f[0]) | ((u32)f2bf(f[1]) << 16);
    u.y = (u32)f2bf(f[2]) | ((u32)f2bf(f[3]) << 16);
    u.z = (u32)f2bf(f[4]) | ((u32)f2bf(f[5]) << 16);
    u.w = (u32)f2bf(f[6]) | ((u32)f2bf(f[7]) << 16);
    return u;
}

// ---- W [L,6,F,H] fp32 -> WT [L,6,H,F] bf16 (transpose via LDS tile) ----
__global__ void convw_k(const float* __restrict__ W, u16* __restrict__ WT) {
    __shared__ float tile[32][33];
    const int lg = blockIdx.z;                  // 0..23
    const int h0 = blockIdx.x * 32, f0 = blockIdx.y * 32;
    const float* Wb = W  + (size_t)lg * F_ * H_;
    u16*        WTb = WT + (size_t)lg * F_ * H_;
    const int tx = threadIdx.x, ty = threadIdx.y;  // 32x8
    #pragma unroll
    for (int i = 0; i < 32; i += 8)
        tile[ty + i][tx] = Wb[(size_t)(f0 + ty + i) * H_ + h0 + tx];
    __syncthreads();
    #pragma unroll
    for (int i = 0; i < 32; i += 8)
        WTb[(size_t)(h0 + ty + i) * F_ + f0 + tx] = f2bf(tile[tx][ty + i]);
}

// ---- x fp32 -> A bf16 ----
__global__ void convx_k(const float* __restrict__ x, u16* __restrict__ A) {
    const int i = blockIdx.x * 256 + threadIdx.x;   // covers RALL*F/4 exactly
    float4 v = ((const float4*)x)[i];
    u32 lo = (u32)f2bf(v.x) | ((u32)f2bf(v.y) << 16);
    u32 hi = (u32)f2bf(v.z) | ((u32)f2bf(v.w) << 16);
    ((uint2*)A)[i] = make_uint2(lo, hi);
}

// ---- per-layer sums of ln_g[l][1][:] / ln_b[l][1][:] ----
__global__ void sumgb_k(const float* __restrict__ lng, const float* __restrict__ lnb,
                        float* __restrict__ sgb) {
    const int l = blockIdx.x, lane = threadIdx.x;
    float s = 0.f, b = 0.f;
    #pragma unroll
    for (int j = 0; j < 8; j++) {
        s += lng[(size_t)l * 6 * 512 + 512 + j * 64 + lane];
        b += lnb[(size_t)l * 6 * 512 + 512 + j * 64 + lane];
    }
    s = wred64(s); b = wred64(b);
    if (lane == 0) { sgb[l * 2] = s; sgb[l * 2 + 1] = b; }
}

// ---- GEMM: Z[m,3072] = A @ WT^T + bias. 128x128, BK=64, 32x32x16 MFMA. ----
// LDS in READ ORDER: block idx = p*8 + s*2 + i holds, at lane slot,
// A[p*64 + i*32 + (lane&31)][kb*64 + s*16 + (lane>>5)*8 .. +7].
// Every ds_read_b128 is base + lane*16 -> linear, zero bank conflicts.
__global__ __launch_bounds__(256) void gemm_k(const u16* __restrict__ A,
                                              const u16* __restrict__ BT,
                                              u16* __restrict__ Z,
                                              const float* __restrict__ bias,
                                              int arow0) {
    __shared__ u16 lsA[8192];   // 16 KB
    __shared__ u16 lsB[8192];
    const int t = threadIdx.x;
    const int ntile = blockIdx.x;                  // 0..23
    const int mtile = blockIdx.y;
    const int ncol0 = ntile * 128;
    const u16* Ab = A  + (size_t)(arow0 + mtile * 128) * F_;
    const u16* Bb = BT + (size_t)ntile * 128 * F_;
    const int lane = t & 63, wv = t >> 6;
    const int rl = lane & 31, hi = lane >> 5;
    const int wm = (wv >> 1) * 64, wn = (wv & 1) * 64;

    f16v acc[2][2];
    #pragma unroll
    for (int i = 0; i < 2; i++)
        #pragma unroll
        for (int j = 0; j < 2; j++) acc[i][j] = 0.0f;

    // staging source offsets: idx = wv*4+jj -> (p = idx>>3, s = (idx>>1)&3, i = idx&1)
    // identical formula serves A and B (q,j roles mirror p,i).
    int goff[4];
    #pragma unroll
    for (int jj = 0; jj < 4; jj++) {
        const int idx = wv * 4 + jj;
        const int p = idx >> 3, s = (idx >> 1) & 3, i = idx & 1;
        goff[jj] = (p * 64 + i * 32 + rl) * F_ + s * 16 + hi * 8;
    }

    for (int kb = 0; kb < 8; ++kb) {
        const int kofs = kb * 64;
        #pragma unroll
        for (int jj = 0; jj < 4; jj++) {
            u16* dst = (u16*)((char*)nullptr) ;  // placeholder avoided below
            const int dof = ((wv * 4 + jj) * 64 + lane) * 8;
            gl_lds16(Ab + goff[jj] + kofs, lsA + dof);
            gl_lds16(Bb + goff[jj] + kofs, lsB + dof);
        }
        __syncthreads();
        #pragma unroll
        for (int s = 0; s < 4; ++s) {
            const int pa = ((wv >> 1) * 8 + s * 2) * 512 + lane * 8;
            const int pb = ((wv & 1) * 8 + s * 2) * 512 + lane * 8;
            s8v fa[2], fb[2];
            #pragma unroll
            for (int i = 0; i < 2; i++) fa[i] = *(const s8v*)(lsA + pa + i * 512);
            #pragma unroll
            for (int j = 0; j < 2; j++) fb[j] = *(const s8v*)(lsB + pb + j * 512);
            #pragma unroll
            for (int i = 0; i < 2; i++)
                #pragma unroll
                for (int j = 0; j < 2; j++)
                    acc[i][j] = __builtin_amdgcn_mfma_f32_32x32x16_bf16(fa[i], fb[j], acc[i][j], 0, 0, 0);
        }
        __syncthreads();
    }

    // epilogue: C/D layout col=lane&31, row=(reg&3)+8*(reg>>2)+4*(lane>>5)
    #pragma unroll
    for (int j = 0; j < 2; j++) {
        const int col = ncol0 + wn + j * 32 + rl;
        const float bv = bias[col];
        #pragma unroll
        for (int i = 0; i < 2; i++) {
            const int mbase = mtile * 128 + wm + i * 32 + hi * 4;
            #pragma unroll
            for (int reg = 0; reg < 16; reg++) {
                const int row = mbase + (reg & 3) + 8 * (reg >> 2);
                Z[(size_t)row * NG + col] = f2bf(acc[i][j][reg] + bv);
            }
        }
    }
}

// ---- sscan: fused stats (gates 1-4) + chunk-local scan. Block = (b, chunk). ----
// Phase 1: row tc is owned by threads [tc*32, tc*32+31]; 32 thr x 64 vals cover
// all 2048 gate values -> one 32-lane shuffle reduce gives exact row stats.
// Phase 2: thread h scans CH steps with stats in LDS.
__global__ __launch_bounds__(512) void sscan_k(const u16* __restrict__ Z,
                                               const float* __restrict__ lngl,
                                               const float* __restrict__ lnbl,
                                               const float* __restrict__ sgb,  // {sg1,sb1}
                                               u16* __restrict__ nbuf,
                                               u16* __restrict__ pbuf,
                                               float* __restrict__ sumP,
                                               float* __restrict__ sumC,
                                               float* __restrict__ sumN) {
    const int b = blockIdx.x, chunk = blockIdx.y;
    const int t = threadIdx.x;
    __shared__ float sst[CH][16];

    // ---- phase 1 ----
    {
        const int tc = t >> 5, l5 = t & 31;
        const int r = (chunk * CH + tc) * 64 + b;
        const u16* zr = Z + (size_t)r * NG + 512;       // gate-1 base
        const float* g1 = lngl + 512;
        float s[4], q[4], wk = 0.f;
        #pragma unroll
        for (int g = 0; g < 4; ++g) { s[g] = 0.f; q[g] = 0.f; }
        #pragma unroll
        for (int g = 0; g < 4; ++g) {
            #pragma unroll
            for (int half = 0; half < 2; ++half) {
                const int col = half * 256 + l5 * 8;
                uint4 u = *(const uint4*)(zr + g * 512 + col);
                float f[8];
                unp8(u, f);
                #pragma unroll
                for (int j = 0; j < 8; j++) { s[g] += f[j]; q[g] += f[j] * f[j]; }
                if (g == 0) {
                    const float4 ga = *(const float4*)(g1 + col);
                    const float4 gb4 = *(const float4*)(g1 + col + 4);
                    wk += ga.x * f[0] + ga.y * f[1] + ga.z * f[2] + ga.w * f[3]
                        + gb4.x * f[4] + gb4.y * f[5] + gb4.z * f[6] + gb4.w * f[7];
                }
            }
        }
        #pragma unroll
        for (int g = 0; g < 4; ++g) { s[g] = wred32(s[g]); q[g] = wred32(q[g]); }
        wk = wred32(wk);
        if (l5 == 0) {
            const float inv = 1.0f / 512.0f;
            float mu1 = 0.f, rs1 = 0.f;
            #pragma unroll
            for (int g = 0; g < 4; ++g) {
                float m = s[g] * inv, e2 = q[g] * inv;
                if (g == 0) { m *= INV_SQRT_H; e2 *= INV_SQRT_H * INV_SQRT_H; }
                const float rs = rsqrtf(fmaxf(e2 - m * m, 0.0f) + 1e-5f);
                sst[tc][1 + g] = m; sst[tc][7 + g] = rs;
                if (g == 0) { mu1 = m; rs1 = rs; }
            }
            sst[tc][12] = rs1 * (INV_SQRT_H * wk - mu1 * sgb[0]) + sgb[1];
        }
    }
    __syncthreads();

    // ---- phase 2 ----
    const int h = t;
    float gg[4], gb[4];
    #pragma unroll
    for (int g = 0; g < 4; ++g) {
        gg[g] = lngl[(g + 1) * 512 + h];
        gb[g] = lnbl[(g + 1) * 512 + h];
    }
    float c = 0.f, n = 0.f, P = 1.f;
    #pragma unroll 4
    for (int tc = 0; tc < CH; ++tc) {
        const int r = (chunk * CH + tc) * 64 + b;
        const u16* zr = Z + (size_t)r * NG + h;
        const float z1 = bu2f(zr[512]);
        const float z2 = bu2f(zr[1024]);
        const float z3 = bu2f(zr[1536]);
        const float z4 = bu2f(zr[2048]);
        const float kk = (z1 * INV_SQRT_H - sst[tc][1]) * sst[tc][7] * gg[0] + gb[0];
        const float vv = (z2 - sst[tc][2]) * sst[tc][8]  * gg[1] + gb[1];
        const float ii = sigm((z3 - sst[tc][3]) * sst[tc][9]  * gg[2] + gb[2]);
        const float ff = sigm((z4 - sst[tc][4]) * sst[tc][10] * gg[3] + gb[3]);
        c = ff * c + ii * (sst[tc][12] * vv);
        n = ff * n + ii * kk;
        P *= ff;
        nbuf[(size_t)r * 512 + h] = f2bf(n);
        pbuf[(size_t)r * 512 + h] = f2bf(P);
    }
    const size_t idx = ((size_t)chunk << 15) + (b << 9) + h;
    sumP[idx] = P; sumC[idx] = c; sumN[idx] = n;
}

// ---- scanB: exact fp32 combine across chunks; emits per-chunk incoming n0. ----
__global__ __launch_bounds__(256) void scanB_k(const float* __restrict__ sumP,
                                               const float* __restrict__ sumC,
                                               const float* __restrict__ sumN,
                                               float* __restrict__ n0buf,
                                               float* __restrict__ cstate,
                                               float* __restrict__ nstate,
                                               float* __restrict__ finals,
                                               int t0, int NC, int l) {
    const int idx = blockIdx.x * 256 + threadIdx.x;   // 0..32767
    float c, n;
    if (t0 == 0) { c = 0.f; n = 0.f; }
    else { c = cstate[idx]; n = nstate[idx]; }
    for (int ch = 0; ch < NC; ++ch) {
        const size_t o = ((size_t)ch << 15) + idx;
        n0buf[o] = n;
        const float P = sumP[o];
        c = sumC[o] + P * c;
        n = sumN[o] + P * n;
    }
    if (t0 + NC * CH == S_) {
        const int b = idx >> 9, h = idx & 511;
        const size_t so = ((size_t)l * B_ + b) * H_ + h;
        finals[(size_t)L_ * B_ * H_ + so] = c;       // c final (exact fp32 combine)
        finals[(size_t)2 * L_ * B_ * H_ + so] = n;   // n final
    } else {
        cstate[idx] = c; nstate[idx] = n;
    }
}

// ---- normh: one wave per (t,b) row. Inline stats gates 0,5; bf16 in-place res. ----
__global__ __launch_bounds__(256) void normh_k(const u16* __restrict__ Z,
                                               const u16* __restrict__ nbuf,
                                               const u16* __restrict__ pbuf,
                                               const float* __restrict__ n0buf,
                                               const float* __restrict__ lngl,
                                               const float* __restrict__ lnbl,
                                               u16* __restrict__ Abf,    // residual in / h out (bf16)
                                               float* __restrict__ outp, // null for l<3
                                               float* __restrict__ finals,
                                               int t0, int l) {
    const int wid = threadIdx.x >> 6, lane = threadIdx.x & 63;
    const int r = blockIdx.x * 4 + wid;
    const int h0 = lane * 8;

    float nl[8], pv[8];
    unp8(*(const uint4*)(nbuf + (size_t)r * 512 + h0), nl);
    unp8(*(const uint4*)(pbuf + (size_t)r * 512 + h0), pv);
    const float* n0r = n0buf + ((size_t)(r >> 10) << 15) + ((size_t)(r & 63) << 9) + h0;
    const float4 na = *(const float4*)(n0r);
    const float4 nb = *(const float4*)(n0r + 4);
    const float n0v[8] = {na.x, na.y, na.z, na.w, nb.x, nb.y, nb.z, nb.w};

    const u16* zr = Z + (size_t)r * NG;
    float z0[8], z5[8];
    unp8(*(const uint4*)(zr + h0), z0);
    unp8(*(const uint4*)(zr + 2560 + h0), z5);

    float nsq = 0.f, s0 = 0.f, q0 = 0.f, s5 = 0.f, q5 = 0.f;
    float nv[8];
    #pragma unroll
    for (int j = 0; j < 8; j++) {
        nv[j] = fmaf(pv[j], n0v[j], nl[j]);
        nsq += nv[j] * nv[j];
        s0 += z0[j]; q0 += z0[j] * z0[j];
        s5 += z5[j]; q5 += z5[j] * z5[j];
    }
    nsq = wred64(nsq);
    s0 = wred64(s0); q0 = wred64(q0);
    s5 = wred64(s5); q5 = wred64(q5);
    const float rinv = 1.0f / (sqrtf(nsq) + 1e-8f);
    const float inv = 1.0f / 512.0f;
    const float mu0 = s0 * inv, mu5 = s5 * inv;
    const float rs0 = rsqrtf(fmaxf(q0 * inv - mu0 * mu0, 0.0f) + 1e-5f);
    const float rs5 = rsqrtf(fmaxf(q5 * inv - mu5 * mu5, 0.0f) + 1e-5f);

    float g0[8], b0[8], g5[8], b5[8];
    #pragma unroll
    for (int j = 0; j < 8; j++) {
        g0[j] = lngl[h0 + j];        b0[j] = lnbl[h0 + j];
        g5[j] = lngl[2560 + h0 + j]; b5[j] = lnbl[2560 + h0 + j];
    }

    const int tl = r >> 6, b = r & 63;
    const int gr = t0 + tl;
    const size_t grow = (((size_t)gr * 64 + b) * 512) + h0;

    float hv[8];
    #pragma unroll
    for (int j = 0; j < 8; j++) {
        const float q  = (z0[j] - mu0) * rs0 * g0[j] + b0[j];
        const float oo = sigm((z5[j] - mu5) * rs5 * g5[j] + b5[j]);
        hv[j] = oo * tanhf_(q * nv[j] * rinv);
    }
    if (l > 0) {
        float rv[8];
        unp8(*(const uint4*)(Abf + grow), rv);
        #pragma unroll
        for (int j = 0; j < 8; j++) hv[j] += rv[j];
    }
    if (outp) {
        #pragma unroll
        for (int j = 0; j < 8; j++) outp[grow + j] = hv[j];
    } else {
        *(uint4*)(Abf + grow) = pck8(hv);
    }

    if (gr == S_ - 1) {
        const size_t so = (((size_t)l * B_ + b) * 512) + h0;
        #pragma unroll
        for (int j = 0; j < 8; j++) finals[so + j] = hv[j];
    }
}

extern "C" void kernel_launch(void* const* d_in, const int* in_sizes, int n_in,
                              void* d_out, int out_size, void* d_ws, size_t ws_size,
                              hipStream_t stream) {
    const float* x   = (const float*)d_in[0];
    const float* W   = (const float*)d_in[1];
    const float* bia = (const float*)d_in[2];
    const float* lng = (const float*)d_in[3];
    const float* lnb = (const float*)d_in[4];
    float* out = (float*)d_out;

    const size_t WT_B = (size_t)L_ * 6 * H_ * F_ * 2;   // 12.58 MB
    const size_t A_B  = (size_t)RALL * F_ * 2;          // 16.78 MB
    const size_t CS_B = (size_t)B_ * H_ * 4;            // 128 KB
    auto zB  = [](int T) { return (size_t)T * B_ * NG * 2; };
    auto nB  = [](int T) { return (size_t)T * B_ * H_ * 2; };
    auto cxB = [](int T) { return (size_t)(T / CH) * B_ * H_ * 4; };
    const size_t base = WT_B + A_B + 2 * CS_B + 65536;

    int T = 16;
    const int cand[3] = {256, 64, 16};
    for (int i = 0; i < 3; i++) {
        const int Tc = cand[i];
        if (ws_size >= base + zB(Tc) + 2 * nB(Tc) + 4 * cxB(Tc)) { T = Tc; break; }
    }
    const int NC = T / CH;

    char* ws = (char*)d_ws;
    size_t off = 0;
    auto take = [&](size_t nb) { size_t o = off; off += (nb + 255) & ~(size_t)255; return o; };
    u16*   WT    = (u16*)  (ws + take(WT_B));
    u16*   Abf   = (u16*)  (ws + take(A_B));
    float* sgb   = (float*)(ws + take(256));
    float* cs    = (float*)(ws + take(CS_B));
    float* ns    = (float*)(ws + take(CS_B));
    u16*   zb    = (u16*)  (ws + take(zB(T)));
    u16*   nbuf  = (u16*)  (ws + take(nB(T)));
    u16*   pbuf  = (u16*)  (ws + take(nB(T)));
    float* sumP  = (float*)(ws + take(cxB(T)));
    float* sumC  = (float*)(ws + take(cxB(T)));
    float* sumN  = (float*)(ws + take(cxB(T)));
    float* n0buf = (float*)(ws + take(cxB(T)));

    convw_k<<<dim3(16, 16, 24), dim3(32, 8), 0, stream>>>(W, WT);
    convx_k<<<dim3(RALL * F_ / 4 / 256), dim3(256), 0, stream>>>(x, Abf);
    sumgb_k<<<dim3(L_), dim3(64), 0, stream>>>(lng, lnb, sgb);

    float* finals = out + (size_t)S_ * B_ * H_;
    for (int l = 0; l < L_; ++l) {
        const u16*   WTl   = WT  + (size_t)l * 6 * H_ * F_;
        const float* biasl = bia + (size_t)l * NG;
        const float* lngl  = lng + (size_t)l * 6 * H_;
        const float* lnbl  = lnb + (size_t)l * 6 * H_;
        for (int j = 0; j < S_ / T; ++j) {
            const int t0 = j * T, arow0 = t0 * B_;
            const int rows = T * B_;
            gemm_k<<<dim3(24, rows / 128), dim3(256), 0, stream>>>(Abf, WTl, zb, biasl, arow0);
            sscan_k<<<dim3(B_, NC), dim3(512), 0, stream>>>(zb, lngl, lnbl, sgb + l * 2,
                                                            nbuf, pbuf, sumP, sumC, sumN);
            scanB_k<<<dim3(128), dim3(256), 0, stream>>>(sumP, sumC, sumN, n0buf,
                                                         cs, ns, finals, t0, NC, l);
            normh_k<<<dim3(rows / 4), dim3(256), 0, stream>>>(zb, nbuf, pbuf, n0buf,
                                                              lngl, lnbl, Abf,
                                                              (l == 3) ? out : (float*)nullptr,
                                                              finals, t0, l);
        }
    }
}